// Round 1
// baseline (422.002 us; speedup 1.0000x reference)
//
#include <hip/hip_runtime.h>
#include <stdint.h>

#define HIST_BINS 65536
#define SORT_CAP 4096

// ws layout (bytes):
//   0        .. 786432  : hist[3][65536] (u32)
//   786432   .. 786448  : cnt[3] + pad
//   786448   .. 786464  : thr[3] + pad
//   786464   .. 884768  : cand[3][SORT_CAP] (u64 composite keys)
//   884768   .. +12*K   : idx[3][K] (sorted selected indices)

__device__ __forceinline__ unsigned fkey(float f) {
    unsigned u = __float_as_uint(f);
    return (u & 0x80000000u) ? ~u : (u | 0x80000000u);  // monotone: bigger float -> bigger key
}

__global__ void zero_kernel(unsigned* __restrict__ p, int n) {
    for (int i = blockIdx.x * blockDim.x + threadIdx.x; i < n; i += gridDim.x * blockDim.x)
        p[i] = 0u;
}

__global__ void hist_kernel(const float* __restrict__ A, const int* __restrict__ bag,
                            unsigned* __restrict__ hist, int N) {
    int c_in = bag[0] & 1, c_out = 1 - c_in;
    for (int i = blockIdx.x * blockDim.x + threadIdx.x; i < N; i += gridDim.x * blockDim.x) {
        float aI = A[2 * i + c_in];
        float aO = A[2 * i + c_out];
        atomicAdd(&hist[0 * HIST_BINS + (fkey(aI)  >> 16)], 1u);
        atomicAdd(&hist[1 * HIST_BINS + (fkey(-aI) >> 16)], 1u);
        atomicAdd(&hist[2 * HIST_BINS + (fkey(aO)  >> 16)], 1u);
    }
}

// One block per selection. Find largest bin T s.t. count(key16 >= T) >= K.
__global__ void __launch_bounds__(1024) thresh_kernel(const unsigned* __restrict__ hist,
                                                      unsigned* __restrict__ thr, int K) {
    __shared__ unsigned s[1024];
    int sel = blockIdx.x;
    const unsigned* h = hist + sel * HIST_BINS;
    int t = threadIdx.x;
    int hi = HIST_BINS - 1 - t * 64;  // thread t covers bins [hi-63 .. hi], from the top
    unsigned sum = 0;
    for (int j = 0; j < 64; ++j) sum += h[hi - j];
    s[t] = sum;
    __syncthreads();
    // inclusive prefix sum over threads (counts from the top of the key space)
    for (int off = 1; off < 1024; off <<= 1) {
        unsigned v = (t >= off) ? s[t - off] : 0u;
        __syncthreads();
        s[t] += v;
        __syncthreads();
    }
    unsigned above = (t == 0) ? 0u : s[t - 1];
    unsigned incl  = s[t];
    if (above < (unsigned)K && incl >= (unsigned)K) {
        unsigned run = above;
        for (int j = 0; j < 64; ++j) {
            run += h[hi - j];
            if (run >= (unsigned)K) { thr[sel] = (unsigned)(hi - j); break; }
        }
    }
}

__global__ void compact_kernel(const float* __restrict__ A, const int* __restrict__ bag,
                               const unsigned* __restrict__ thr, unsigned* __restrict__ cnt,
                               unsigned long long* __restrict__ cand, int N) {
    int c_in = bag[0] & 1, c_out = 1 - c_in;
    unsigned t0 = thr[0], t1 = thr[1], t2 = thr[2];
    for (int i = blockIdx.x * blockDim.x + threadIdx.x; i < N; i += gridDim.x * blockDim.x) {
        float aI = A[2 * i + c_in];
        float aO = A[2 * i + c_out];
        unsigned k0 = fkey(aI), k1 = fkey(-aI), k2 = fkey(aO);
        // composite: key desc, then index asc (~i so larger composite = smaller index)
        if ((k0 >> 16) >= t0) {
            unsigned p = atomicAdd(&cnt[0], 1u);
            if (p < SORT_CAP) cand[0 * SORT_CAP + p] = ((unsigned long long)k0 << 32) | (unsigned)(~i);
        }
        if ((k1 >> 16) >= t1) {
            unsigned p = atomicAdd(&cnt[1], 1u);
            if (p < SORT_CAP) cand[1 * SORT_CAP + p] = ((unsigned long long)k1 << 32) | (unsigned)(~i);
        }
        if ((k2 >> 16) >= t2) {
            unsigned p = atomicAdd(&cnt[2], 1u);
            if (p < SORT_CAP) cand[2 * SORT_CAP + p] = ((unsigned long long)k2 << 32) | (unsigned)(~i);
        }
    }
}

// One block per selection: exact rank of each candidate by counting, write top-K indices in order.
__global__ void __launch_bounds__(1024) rank_kernel(const unsigned* __restrict__ cnt,
                                                    const unsigned long long* __restrict__ cand,
                                                    int* __restrict__ idx, int K) {
    __shared__ unsigned long long s[SORT_CAP];
    int sel = blockIdx.x;
    unsigned C = cnt[sel];
    if (C > SORT_CAP) C = SORT_CAP;
    const unsigned long long* c = cand + sel * SORT_CAP;
    for (unsigned i = threadIdx.x; i < C; i += blockDim.x) s[i] = c[i];
    __syncthreads();
    for (unsigned i = threadIdx.x; i < C; i += blockDim.x) {
        unsigned long long me = s[i];
        unsigned r = 0;
        for (unsigned j = 0; j < C; ++j) r += (s[j] > me) ? 1u : 0u;
        if (r < (unsigned)K) idx[sel * K + (int)r] = (int)(~(unsigned)me);
    }
}

// One wave per output row: gather h row, dot with W[:,0], W[:,1], softmax, write outputs.
__global__ void out_kernel(const float* __restrict__ h, const float* __restrict__ W,
                           const float* __restrict__ b, const int* __restrict__ idx,
                           float* __restrict__ out, int K, int D) {
    __shared__ float sW[1024];  // W is (D,2) row-major, D <= 512
    int DW = 2 * D;
    for (int i = threadIdx.x; i < DW; i += blockDim.x) sW[i] = W[i];
    __syncthreads();
    int lane = threadIdx.x & 63;
    int wave = threadIdx.x >> 6;
    int wpb  = blockDim.x >> 6;
    int M = 3 * K;
    for (int r = blockIdx.x * wpb + wave; r < M; r += gridDim.x * wpb) {
        int src = idx[r];
        const float* row = h + (long long)src * D;
        float acc0 = 0.f, acc1 = 0.f;
        for (int d = lane * 4; d < D; d += 256) {
            float4 v = *(const float4*)(row + d);
            acc0 += v.x * sW[2*d]     + v.y * sW[2*d + 2] + v.z * sW[2*d + 4] + v.w * sW[2*d + 6];
            acc1 += v.x * sW[2*d + 1] + v.y * sW[2*d + 3] + v.z * sW[2*d + 5] + v.w * sW[2*d + 7];
        }
        for (int off = 32; off > 0; off >>= 1) {
            acc0 += __shfl_down(acc0, off, 64);
            acc1 += __shfl_down(acc1, off, 64);
        }
        if (lane == 0) {
            float z0 = acc0 + b[0];
            float z1 = acc1 + b[1];
            float m = fmaxf(z0, z1);
            float e0 = expf(z0 - m), e1 = expf(z1 - m);
            float inv = 1.0f / (e0 + e1);
            out[r] = (r < K) ? 1.0f : 0.0f;          // labels: [1]*K, [0]*K, [0]*K
            out[M + 2*r]         = z0;               // logits_unnorm (M,1,2)
            out[M + 2*r + 1]     = z1;
            out[3*M + 2*r]       = e0 * inv;         // softmax (M,1,2)
            out[3*M + 2*r + 1]   = e1 * inv;
        }
    }
}

extern "C" void kernel_launch(void* const* d_in, const int* in_sizes, int n_in,
                              void* d_out, int out_size, void* d_ws, size_t ws_size,
                              hipStream_t stream) {
    const float* h   = (const float*)d_in[0];
    const float* A   = (const float*)d_in[1];
    const float* W   = (const float*)d_in[2];
    const float* b   = (const float*)d_in[3];
    const int*   bag = (const int*)d_in[4];

    int N = in_sizes[1] / 2;          // A is (N,1,2)
    int D = in_sizes[0] / N;          // h is (N,1,D)
    int K = (int)(0.02 * N);          // matches Python int(TOP_K_PERCENT * N)
    if (K == 0) K = 8;

    char* ws = (char*)d_ws;
    unsigned*            hist = (unsigned*)ws;
    unsigned*            cnt  = (unsigned*)(ws + 786432);
    unsigned*            thr  = (unsigned*)(ws + 786448);
    unsigned long long*  cand = (unsigned long long*)(ws + 786464);
    int*                 idx  = (int*)(ws + 786464 + 3 * SORT_CAP * 8);

    int zwords = (786432 + 16) / 4;   // hist + counters
    zero_kernel<<<512, 256, 0, stream>>>(hist, zwords);

    int nb = (N + 255) / 256;
    if (nb > 1024) nb = 1024;
    hist_kernel<<<nb, 256, 0, stream>>>(A, bag, hist, N);
    thresh_kernel<<<3, 1024, 0, stream>>>(hist, thr, K);
    compact_kernel<<<nb, 256, 0, stream>>>(A, bag, thr, cnt, cand, N);
    rank_kernel<<<3, 1024, 0, stream>>>(cnt, cand, idx, K);

    int M = 3 * K;
    int blocks = (M + 3) / 4;         // 4 waves/block, one row per wave
    out_kernel<<<blocks, 256, 0, stream>>>(h, W, b, idx, (float*)d_out, K, D);
}

// Round 2
// 374.055 us; speedup vs baseline: 1.1282x; 1.1282x over previous
//
#include <hip/hip_runtime.h>
#include <stdint.h>

#define HIST_BINS 65536
#define SORT_CAP 4096

// ws layout (bytes):
//   0        .. 786432  : hist[3][65536] (u32)
//   786432   .. 786444  : cnt[3]
//   786448   .. 786460  : thr[3]
//   786464   .. 884768  : cand[3][SORT_CAP] (u64 composite keys)
//   884768   .. +12*K   : idx[3][K] (sorted selected indices)

__device__ __forceinline__ unsigned fkey(float f) {
    unsigned u = __float_as_uint(f);
    return (u & 0x80000000u) ? ~u : (u | 0x80000000u);  // monotone: bigger float -> bigger key
}

__global__ void zero_kernel(unsigned* __restrict__ p, int n) {
    int i = blockIdx.x * blockDim.x + threadIdx.x;
    int stride = gridDim.x * blockDim.x;
    for (; i < n; i += stride) p[i] = 0u;
}

__global__ void hist_kernel(const float* __restrict__ A, const int* __restrict__ bag,
                            unsigned* __restrict__ hist, int N) {
    int c_in = bag[0] & 1, c_out = 1 - c_in;
    int i = blockIdx.x * blockDim.x + threadIdx.x;
    int stride = gridDim.x * blockDim.x;
    for (; i < N; i += stride) {
        float aI = A[2 * i + c_in];
        float aO = A[2 * i + c_out];
        unsigned k0 = fkey(aI);
        atomicAdd(&hist[0 * HIST_BINS + (k0 >> 16)], 1u);
        atomicAdd(&hist[1 * HIST_BINS + ((~k0) >> 16)], 1u);   // fkey(-x) == ~fkey(x)
        atomicAdd(&hist[2 * HIST_BINS + (fkey(aO) >> 16)], 1u);
    }
}

// One block per selection. T = largest bin with count(key16 >= T) >= K.
// Using suffix(b) = N - cum(b), cum(b)=count(bins < b): T is the unique b with
// cum(b) <= N-K < cum(b)+h[b]. Ascending coalesced scan, shuffle-based prefix.
__global__ void __launch_bounds__(1024) thresh_kernel(const unsigned* __restrict__ hist,
                                                      unsigned* __restrict__ thr,
                                                      int N, int K) {
    __shared__ unsigned wsum[16];
    int sel = blockIdx.x;
    const uint4* hv = (const uint4*)(hist + sel * HIST_BINS);
    int t = threadIdx.x;
    int lane = t & 63, wid = t >> 6;
    int base4 = t * 16;                         // 16 uint4 = 64 bins per thread
    unsigned mySum = 0;
    #pragma unroll
    for (int v = 0; v < 16; ++v) {
        uint4 q = hv[base4 + v];
        mySum += q.x + q.y + q.z + q.w;
    }
    // inclusive scan over 1024 threads: wave shuffle + cross-wave LDS
    unsigned x = mySum;
    #pragma unroll
    for (int off = 1; off < 64; off <<= 1) {
        unsigned v = __shfl_up(x, off, 64);
        if (lane >= off) x += v;
    }
    if (lane == 63) wsum[wid] = x;
    __syncthreads();
    if (t < 16) {
        unsigned w = wsum[t];
        #pragma unroll
        for (int off = 1; off < 16; off <<= 1) {
            unsigned v = __shfl_up(w, off, 64);
            if (t >= off) w += v;
        }
        wsum[t] = w;                            // inclusive wave totals
    }
    __syncthreads();
    unsigned cum = ((wid == 0) ? 0u : wsum[wid - 1]) + x - mySum;  // excl prefix of chunk
    unsigned S = (unsigned)(N - K);
    if (cum <= S && cum + mySum > S) {          // crossing is inside this thread's chunk
        #pragma unroll
        for (int v = 0; v < 16; ++v) {
            uint4 q = hv[base4 + v];            // L1-hot reload
            unsigned a[4] = {q.x, q.y, q.z, q.w};
            for (int j = 0; j < 4; ++j) {
                unsigned c2 = cum + a[j];
                if (cum <= S && c2 > S) thr[sel] = (unsigned)(t * 64 + v * 4 + j);
                cum = c2;
            }
        }
    }
}

__global__ void compact_kernel(const float* __restrict__ A, const int* __restrict__ bag,
                               const unsigned* __restrict__ thr, unsigned* __restrict__ cnt,
                               unsigned long long* __restrict__ cand, int N) {
    int c_in = bag[0] & 1, c_out = 1 - c_in;
    unsigned t0 = thr[0], t1 = thr[1], t2 = thr[2];
    int i = blockIdx.x * blockDim.x + threadIdx.x;
    int stride = gridDim.x * blockDim.x;
    for (; i < N; i += stride) {
        float aI = A[2 * i + c_in];
        float aO = A[2 * i + c_out];
        unsigned k0 = fkey(aI), k1 = ~k0, k2 = fkey(aO);
        // composite: key desc, then index asc (~i: larger composite = smaller index)
        if ((k0 >> 16) >= t0) {
            unsigned p = atomicAdd(&cnt[0], 1u);
            if (p < SORT_CAP) cand[0 * SORT_CAP + p] = ((unsigned long long)k0 << 32) | (unsigned)(~i);
        }
        if ((k1 >> 16) >= t1) {
            unsigned p = atomicAdd(&cnt[1], 1u);
            if (p < SORT_CAP) cand[1 * SORT_CAP + p] = ((unsigned long long)k1 << 32) | (unsigned)(~i);
        }
        if ((k2 >> 16) >= t2) {
            unsigned p = atomicAdd(&cnt[2], 1u);
            if (p < SORT_CAP) cand[2 * SORT_CAP + p] = ((unsigned long long)k2 << 32) | (unsigned)(~i);
        }
    }
}

// 4 blocks per selection; exact rank-by-count among <=~2100 candidates.
// Inner loop reads the same LDS word across all lanes -> broadcast, conflict-free.
__global__ void __launch_bounds__(1024) rank_kernel(const unsigned* __restrict__ cnt,
                                                    const unsigned long long* __restrict__ cand,
                                                    int* __restrict__ idx, int K) {
    __shared__ unsigned long long s[SORT_CAP];
    int sel = blockIdx.x >> 2;
    unsigned part = blockIdx.x & 3;
    unsigned C = cnt[sel];
    if (C > SORT_CAP) C = SORT_CAP;
    const unsigned long long* c = cand + sel * SORT_CAP;
    for (unsigned i = threadIdx.x; i < C; i += blockDim.x) s[i] = c[i];
    __syncthreads();
    for (unsigned i = part + 4u * threadIdx.x; i < C; i += 4u * blockDim.x) {
        unsigned long long me = s[i];
        unsigned r = 0, j = 0;
        for (; j + 4 <= C; j += 4) {
            r += (s[j]     > me);
            r += (s[j + 1] > me);
            r += (s[j + 2] > me);
            r += (s[j + 3] > me);
        }
        for (; j < C; ++j) r += (s[j] > me);
        if (r < (unsigned)K) idx[sel * K + (int)r] = (int)(~(unsigned)me);
    }
}

// One wave per output row: gather h row (the real HBM traffic), dot with W (L1-resident),
// softmax, write labels + logits + probs.
__global__ void out_kernel(const float* __restrict__ h, const float* __restrict__ W,
                           const float* __restrict__ b, const int* __restrict__ idx,
                           float* __restrict__ out, int K, int D) {
    int lane = threadIdx.x & 63;
    int wave = threadIdx.x >> 6;
    int wpb  = blockDim.x >> 6;
    int M = 3 * K;
    int r = blockIdx.x * wpb + wave;
    if (r >= M) return;
    int src = idx[r];
    const float* row = h + (long long)src * D;
    float acc0 = 0.f, acc1 = 0.f;
    for (int d = lane * 4; d < D; d += 256) {
        float4 v  = *(const float4*)(row + d);
        float4 w0 = *(const float4*)(W + 2 * d);       // rows d,d+1 (c0,c1,c0,c1)
        float4 w1 = *(const float4*)(W + 2 * d + 4);   // rows d+2,d+3
        acc0 += v.x * w0.x + v.y * w0.z + v.z * w1.x + v.w * w1.z;
        acc1 += v.x * w0.y + v.y * w0.w + v.z * w1.y + v.w * w1.w;
    }
    #pragma unroll
    for (int off = 32; off > 0; off >>= 1) {
        acc0 += __shfl_down(acc0, off, 64);
        acc1 += __shfl_down(acc1, off, 64);
    }
    if (lane == 0) {
        float z0 = acc0 + b[0];
        float z1 = acc1 + b[1];
        float m = fmaxf(z0, z1);
        float e0 = __expf(z0 - m), e1 = __expf(z1 - m);
        float inv = 1.0f / (e0 + e1);
        out[r] = (r < K) ? 1.0f : 0.0f;            // labels: [1]*K, [0]*K, [0]*K
        out[M + 2 * r]         = z0;               // logits_unnorm (M,1,2)
        out[M + 2 * r + 1]     = z1;
        out[3 * M + 2 * r]     = e0 * inv;         // softmax (M,1,2)
        out[3 * M + 2 * r + 1] = e1 * inv;
    }
}

extern "C" void kernel_launch(void* const* d_in, const int* in_sizes, int n_in,
                              void* d_out, int out_size, void* d_ws, size_t ws_size,
                              hipStream_t stream) {
    const float* h   = (const float*)d_in[0];
    const float* A   = (const float*)d_in[1];
    const float* W   = (const float*)d_in[2];
    const float* b   = (const float*)d_in[3];
    const int*   bag = (const int*)d_in[4];

    int N = in_sizes[1] / 2;          // A is (N,1,2)
    int D = in_sizes[0] / N;          // h is (N,1,D)
    int K = (int)(0.02 * N);          // matches Python int(TOP_K_PERCENT * N)
    if (K == 0) K = 8;

    char* ws = (char*)d_ws;
    unsigned*            hist = (unsigned*)ws;
    unsigned*            cnt  = (unsigned*)(ws + 786432);
    unsigned*            thr  = (unsigned*)(ws + 786448);
    unsigned long long*  cand = (unsigned long long*)(ws + 786464);
    int*                 idx  = (int*)(ws + 786464 + 3 * SORT_CAP * 8);

    int zwords = 3 * HIST_BINS + 4;   // hist + cnt
    zero_kernel<<<256, 256, 0, stream>>>(hist, zwords);

    int nb = (N + 255) / 256;
    if (nb > 1024) nb = 1024;
    hist_kernel<<<nb, 256, 0, stream>>>(A, bag, hist, N);
    thresh_kernel<<<3, 1024, 0, stream>>>(hist, thr, N, K);
    compact_kernel<<<nb, 256, 0, stream>>>(A, bag, thr, cnt, cand, N);
    rank_kernel<<<12, 1024, 0, stream>>>(cnt, cand, idx, K);

    int M = 3 * K;
    out_kernel<<<(M + 3) / 4, 256, 0, stream>>>(h, W, b, idx, (float*)d_out, K, D);
}